// Round 7
// baseline (247.191 us; speedup 1.0000x reference)
//
#include <hip/hip_runtime.h>

#define TSC_OUT_LEN 16384
#define TSC_ENC_LEN 16368   // 16384 - 16384/1024
#define TSC_ROWS 16         // rows processed per block

// readfirstlane on a float: forces a block/wave-uniform value into an SGPR.
__device__ __forceinline__ float tsc_rfl(float x) {
    return __uint_as_float(__builtin_amdgcn_readfirstlane(__float_as_uint(x)));
}

// One row's in-flight coefficients: 13 floats (d1, d2, c3..c10).
struct TscLd {
    float4 d1;
    float2 d2;
    float  ct[8];   // c3..c10 — indexed only with compile-time constants
};

// out[b,j] = sum_{e=1..10} data[b, off_e + (j>>e)] * weights[(2^e-1) + (j&(2^e-1))] + sum_e bias[e-1]
//
// R6 post-mortem: sequential-burst + DMA staging gave minimal clean traffic
// and the SAME 85 us / 2.4 TB/s as R0/R2/R4 -> access-pattern theory dead.
// (R5's "3.45 TB/s" was scratch-traffic inflation; useful BW was 1.77.)
// fillBufferAligned does 6.5 TB/s of writes at 9% occupancy -> writes are
// free-flowing; the wall is READ MLP: each wave holds only ~2 KB of reads in
// flight, then stalls a full loaded latency (Little's law needs ~22 KB/CU
// sustained for 6.3 TB/s; we sustain ~10-20 KB/CU).
//
// R7 = R3's 4-deep row pipeline with the two defects fixed:
//  - no __launch_bounds__ min-waves clamp (R3's (256,4) capped VGPR at 64 and
//    forced the pipeline buffers into scratch: +190 MB traffic). Grid 1024 =
//    4 blocks/CU caps occupancy at 16 waves/CU anyway, so VGPR<=128 is free.
//  - e=4..10 weights are re-read from LDS inside the compute body (R0 ran
//    this pattern at VGPR 36; reads are 2-way/broadcast b128, cheap) instead
//    of 56 pinned VGPRs. 4 row-buffers x 13 floats + acc + addrs ~= 100 VGPR.
// Each wave keeps 3 rows (~4.5 KB) of reads permanently in flight ->
// ~72 KB/CU sustained outstanding, 3-6x previous rounds.
__global__ __launch_bounds__(256) void tsc_transpose_kernel(
    const float* __restrict__ data,
    const float* __restrict__ weights,
    const float* __restrict__ bias,
    float* __restrict__ out)
{
    __shared__ float wl[2048];
    const int tid = threadIdx.x;
    for (int i = tid; i < 2047; i += 256) wl[i + 1] = weights[i];
    __syncthreads();

    const int tile = blockIdx.x & 7;             // output column tile (0..7)
    const int rg   = blockIdx.x >> 3;            // row group (0..127)
    const int j0   = (tile << 11) + (tid << 3);  // fixed 8-aligned output column

    // Sum of all per-scale biases — one constant added to every output.
    float bs = 0.0f;
#pragma unroll
    for (int i = 0; i < 10; ++i) bs += bias[i];

    // e=1..3 weights: identical for every thread in the block -> SGPRs.
    const float w1a = tsc_rfl(wl[2]), w1b = tsc_rfl(wl[3]);
    const float w2a = tsc_rfl(wl[4]), w2b = tsc_rfl(wl[5]);
    const float w2c = tsc_rfl(wl[6]), w2d = tsc_rfl(wl[7]);
    float w3[8];
#pragma unroll
    for (int i = 0; i < 8; ++i) w3[i] = tsc_rfl(wl[8 + i]);

    // e=4..10 weight LDS offsets (per-thread, loop-invariant; reads happen in
    // the compute body so the values are short-lived temporaries, not pinned).
    int kbA[7];
#pragma unroll
    for (int e = 4; e <= 10; ++e) {
        const int w = 1 << e;
        kbA[e - 4] = w + (j0 & (w - 1));   // 8-aligned -> 16B-aligned reads
    }

    // Loop-invariant per-lane element offsets into a data row.
    const int i1 = (j0 >> 1);                  // float4, 16B aligned
    const int i2 = 8192  + (j0 >> 2);          // float2, 8B aligned
    const int i3 = 12288 + (j0 >> 3);
    const int i4 = 14336 + (j0 >> 4);
    const int i5 = 15360 + (j0 >> 5);
    const int i6 = 15872 + (j0 >> 6);
    const int i7 = 16128 + (j0 >> 7);
    const int i8 = 16256 + (j0 >> 8);
    const int i9  = 16320 + __builtin_amdgcn_readfirstlane(j0 >> 9);
    const int i10 = 16352 + __builtin_amdgcn_readfirstlane(j0 >> 10);

    const float* drow = data + (size_t)rg * TSC_ROWS * TSC_ENC_LEN;
    float*       orow = out  + (size_t)rg * TSC_ROWS * TSC_OUT_LEN + j0;

    auto issue = [&](const float* dp, TscLd& L) {
        L.d1    = *reinterpret_cast<const float4*>(dp + i1);
        L.d2    = *reinterpret_cast<const float2*>(dp + i2);
        L.ct[0] = dp[i3];
        L.ct[1] = dp[i4];
        L.ct[2] = dp[i5];
        L.ct[3] = dp[i6];
        L.ct[4] = dp[i7];
        L.ct[5] = dp[i8];
        L.ct[6] = dp[i9];
        L.ct[7] = dp[i10];
    };

    auto compute_store = [&](const TscLd& L, float* op) {
        float a0 = bs, a1 = bs, a2 = bs, a3 = bs;
        float a4 = bs, a5 = bs, a6 = bs, a7 = bs;
        // e = 1 (SGPR weights)
        a0 = fmaf(L.d1.x, w1a, a0); a1 = fmaf(L.d1.x, w1b, a1);
        a2 = fmaf(L.d1.y, w1a, a2); a3 = fmaf(L.d1.y, w1b, a3);
        a4 = fmaf(L.d1.z, w1a, a4); a5 = fmaf(L.d1.z, w1b, a5);
        a6 = fmaf(L.d1.w, w1a, a6); a7 = fmaf(L.d1.w, w1b, a7);
        // e = 2 (SGPR weights)
        a0 = fmaf(L.d2.x, w2a, a0); a1 = fmaf(L.d2.x, w2b, a1);
        a2 = fmaf(L.d2.x, w2c, a2); a3 = fmaf(L.d2.x, w2d, a3);
        a4 = fmaf(L.d2.y, w2a, a4); a5 = fmaf(L.d2.y, w2b, a5);
        a6 = fmaf(L.d2.y, w2c, a6); a7 = fmaf(L.d2.y, w2d, a7);
        // e = 3 (SGPR weights)
        a0 = fmaf(L.ct[0], w3[0], a0); a1 = fmaf(L.ct[0], w3[1], a1);
        a2 = fmaf(L.ct[0], w3[2], a2); a3 = fmaf(L.ct[0], w3[3], a3);
        a4 = fmaf(L.ct[0], w3[4], a4); a5 = fmaf(L.ct[0], w3[5], a5);
        a6 = fmaf(L.ct[0], w3[6], a6); a7 = fmaf(L.ct[0], w3[7], a7);
        // e = 4..10: weights streamed from LDS (short-lived temporaries)
#pragma unroll
        for (int e = 4; e <= 10; ++e) {
            const int   i  = e - 4;
            const float c  = L.ct[e - 3];
            const float4 k0 = *reinterpret_cast<const float4*>(&wl[kbA[i]]);
            const float4 k1 = *reinterpret_cast<const float4*>(&wl[kbA[i] + 4]);
            a0 = fmaf(c, k0.x, a0); a1 = fmaf(c, k0.y, a1);
            a2 = fmaf(c, k0.z, a2); a3 = fmaf(c, k0.w, a3);
            a4 = fmaf(c, k1.x, a4); a5 = fmaf(c, k1.y, a5);
            a6 = fmaf(c, k1.z, a6); a7 = fmaf(c, k1.w, a7);
        }
        float4* o4 = reinterpret_cast<float4*>(op);
        o4[0] = make_float4(a0, a1, a2, a3);
        o4[1] = make_float4(a4, a5, a6, a7);
    };

    // 4-deep software pipeline: three rows' reads always in flight. Static
    // buffer rotation via 4x-unrolled body (no runtime indexing -> no scratch).
    TscLd L0, L1, L2, L3;
    issue(drow + 0 * TSC_ENC_LEN, L0);
    issue(drow + 1 * TSC_ENC_LEN, L1);
    issue(drow + 2 * TSC_ENC_LEN, L2);
#pragma unroll 1
    for (int r = 0; r < TSC_ROWS - 4; r += 4) {
        issue(drow + 3 * TSC_ENC_LEN, L3); compute_store(L0, orow);
        issue(drow + 4 * TSC_ENC_LEN, L0); compute_store(L1, orow + 1 * TSC_OUT_LEN);
        issue(drow + 5 * TSC_ENC_LEN, L1); compute_store(L2, orow + 2 * TSC_OUT_LEN);
        issue(drow + 6 * TSC_ENC_LEN, L2); compute_store(L3, orow + 3 * TSC_OUT_LEN);
        drow += 4 * TSC_ENC_LEN;
        orow += 4 * TSC_OUT_LEN;
    }
    // Epilogue: rows 12..15 (L0=r12, L1=r13, L2=r14 already in flight).
    issue(drow + 3 * TSC_ENC_LEN, L3);
    compute_store(L0, orow);
    compute_store(L1, orow + 1 * TSC_OUT_LEN);
    compute_store(L2, orow + 2 * TSC_OUT_LEN);
    compute_store(L3, orow + 3 * TSC_OUT_LEN);
}

extern "C" void kernel_launch(void* const* d_in, const int* in_sizes, int n_in,
                              void* d_out, int out_size, void* d_ws, size_t ws_size,
                              hipStream_t stream) {
    const float* data    = (const float*)d_in[0];
    const float* weights = (const float*)d_in[1];
    const float* bias    = (const float*)d_in[2];
    float* out = (float*)d_out;

    const int B = in_sizes[0] / TSC_ENC_LEN;   // 2048
    dim3 grid((B / TSC_ROWS) * 8);             // 8 column tiles x 128 row groups = 1024
    dim3 block(256);
    tsc_transpose_kernel<<<grid, block, 0, stream>>>(data, weights, bias, out);
}

// Round 8
// 243.079 us; speedup vs baseline: 1.0169x; 1.0169x over previous
//
#include <hip/hip_runtime.h>

#define TSC_OUT_LEN 16384
#define TSC_ENC_LEN 16368   // 16384 - 16384/1024

// Counted wait: leave the newest 8 VMEM ops (next chunk's DMA+e1) in flight,
// require everything older (current chunk's DMA) complete. NEVER vmcnt(0) in
// the steady state.
#define TSC_WAIT8() asm volatile("s_waitcnt vmcnt(8)" ::: "memory")
// Raw barrier (no vmcnt drain, unlike __syncthreads). Memory clobber keeps
// ds_reads from hoisting above it.
#define TSC_BAR() do { __builtin_amdgcn_s_barrier(); asm volatile("" ::: "memory"); } while (0)

// readfirstlane on a float: forces a block/wave-uniform value into an SGPR.
__device__ __forceinline__ float tsc_rfl(float x) {
    return __uint_as_float(__builtin_amdgcn_readfirstlane(__float_as_uint(x)));
}

// out[b,j] = sum_{e=1..10} data[b, off_e + (j>>e)] * weights[(2^e-1) + (j&(2^e-1))] + sum_e bias[e-1]
//
// R7 post-mortem: register-target read pipelines leave the wave owning the
// latency (it must block on s_waitcnt for its own dest regs); every clean
// structure pins at 2.5 TB/s. But R3/R5 (scratch streams off the dependency
// chain) pushed serviced HBM to 2.9-3.45 TB/s, and fillBuffer writes at 6.5:
// traffic NOT on a dependency chain flows fast.
//
// R8: decouple read issue from compute. Persistent blocks (grid 1024), each
// owns 4 chunks = 2 rows x 2 halves. Per chunk, e=2..10 coefficients
// (16 KB) are DMA'd global->LDS via global_load_lds (fire-and-forget, zero
// dest regs) into a DOUBLE buffer; e=1 (16 KB, the sequential half of the
// reads) goes direct-to-register one chunk ahead (2 static reg sets).
// Steady-state loop per chunk:
//   wait vmcnt(8)   -- chunk c's 8 ops done; chunk c+1's 8 stay in flight
//   s_barrier       -- all waves' chunk-c data visible; prev buf readers done
//   issue chunk c+1 -- 4 DMA + 4 e1 loads (in flight through compute c)
//   compute c       -- from LDS buf[c&1] + e1 regs; weights from LDS (keeps
//                      VGPR ~<=100; R3 proved pinned-weight pipelines spill)
// ~32 KB/block of reads permanently in flight (~128 KB/CU at 4 blocks/CU),
// outstanding even while waves sit at barriers.
// dL chunk layout (floats): e2 [0,2048) e3 [2048,3072) e4 [3072,3584)
// e5 [3584,3840) e6 [3840,3968) e7 [3968,4032) e8 [4032,4064)
// e9 [4064,4080) e10 [4080,4088); slots 1022/1023 clamped padding.
__global__ __launch_bounds__(256) void tsc_transpose_kernel(
    const float* __restrict__ data,
    const float* __restrict__ weights,
    const float* __restrict__ bias,
    float* __restrict__ out)
{
    __shared__ float wl[2048];
    __shared__ __align__(16) float dL[2][4096];

    const int tid = threadIdx.x;
    for (int i = tid; i < 2047; i += 256) wl[i + 1] = weights[i];
    __syncthreads();   // prologue-only full drain (wl ds_writes)

    // ---- per-thread DMA slot decode (loop-invariant) -----------------------
    const int lane = tid & 63;
    const int wu   = __builtin_amdgcn_readfirstlane(tid >> 6);
    int off0[4], offh[4], ldsb[4]; bool val[4];
#pragma unroll
    for (int k = 0; k < 4; ++k) {
        const int cid = k + (wu << 2);      // wave-uniform chunk id 0..15
        const int s   = lane + (cid << 6);  // float4 slot 0..1023
        int e, base;
        if      (s < 512)  { e = 2;  base = 0;    }
        else if (s < 768)  { e = 3;  base = 512;  }
        else if (s < 896)  { e = 4;  base = 768;  }
        else if (s < 960)  { e = 5;  base = 896;  }
        else if (s < 992)  { e = 6;  base = 960;  }
        else if (s < 1008) { e = 7;  base = 992;  }
        else if (s < 1016) { e = 8;  base = 1008; }
        else if (s < 1020) { e = 9;  base = 1016; }
        else               { e = 10; base = 1020; }
        off0[k] = TSC_OUT_LEN - (32768 >> e) + ((s - base) << 2);
        offh[k] = 1 << (13 - e);            // half-1 extra offset
        ldsb[k] = cid << 8;                 // float offset into chunk buffer
        val[k]  = (s < 1022);
    }

    // Sum of all per-scale biases — one constant added to every output.
    float bs = 0.0f;
#pragma unroll
    for (int i = 0; i < 10; ++i) bs += bias[i];

    // e=1..3 weights -> SGPRs.
    const float w1a = tsc_rfl(wl[2]), w1b = tsc_rfl(wl[3]);
    const float w2a = tsc_rfl(wl[4]), w2b = tsc_rfl(wl[5]);
    const float w2c = tsc_rfl(wl[6]), w2d = tsc_rfl(wl[7]);
    float w3[8];
#pragma unroll
    for (int i = 0; i < 8; ++i) w3[i] = tsc_rfl(wl[8 + i]);

    // e=4..10 weight LDS base offsets (values re-read in the compute body).
    const int j8 = tid << 3;
    int kbA[7];
#pragma unroll
    for (int e = 4; e <= 10; ++e) {
        const int w = 1 << e;
        kbA[e - 4] = w + (j8 & (w - 1));    // 16B-aligned b128 reads
    }

    const int b0 = blockIdx.x << 1;         // two consecutive rows per block
    const float* dr0 = data + (size_t)b0 * TSC_ENC_LEN;
    const float* dr1 = dr0 + TSC_ENC_LEN;

    auto dma = [&](const float* dr, int hf, float* buf) {
#pragma unroll
        for (int k = 0; k < 4; ++k) {
            const float* gs = val[k] ? (dr + off0[k] + (hf ? offh[k] : 0)) : dr;
            __builtin_amdgcn_global_load_lds(
                (const __attribute__((address_space(1))) unsigned int*)gs,
                (__attribute__((address_space(3))) unsigned int*)(buf + ldsb[k]),
                16, 0, 0);
        }
    };

#define TSC_LDE1(DR, HF, CA, CB, CC, CD) do {                               \
        const float* p1_ = (DR) + ((HF) << 12) + (tid << 2);                \
        CA = *reinterpret_cast<const float4*>(p1_);                         \
        CB = *reinterpret_cast<const float4*>(p1_ + 1024);                  \
        CC = *reinterpret_cast<const float4*>(p1_ + 2048);                  \
        CD = *reinterpret_cast<const float4*>(p1_ + 3072);                  \
    } while (0)

#define TSC_ITER(DLB, IT, C1, OROW) do {                                    \
        const int jl = ((IT) << 11) + j8;                                   \
        const float2 c2 = *reinterpret_cast<const float2*>(&(DLB)[jl >> 2]);\
        const float c3  = (DLB)[2048 + (jl >> 3)];                          \
        const float c4  = (DLB)[3072 + (jl >> 4)];                          \
        const float c5  = (DLB)[3584 + (jl >> 5)];                          \
        const float c6  = (DLB)[3840 + (jl >> 6)];                          \
        const float c7  = (DLB)[3968 + (jl >> 7)];                          \
        const float c8  = (DLB)[4032 + (jl >> 8)];                          \
        const float c9  = (DLB)[4064 + (jl >> 9)];                          \
        const float c10 = (DLB)[4080 + (jl >> 10)];                         \
        float a0 = bs, a1 = bs, a2 = bs, a3 = bs;                           \
        float a4 = bs, a5 = bs, a6 = bs, a7 = bs;                           \
        a0 = fmaf((C1).x, w1a, a0); a1 = fmaf((C1).x, w1b, a1);             \
        a2 = fmaf((C1).y, w1a, a2); a3 = fmaf((C1).y, w1b, a3);             \
        a4 = fmaf((C1).z, w1a, a4); a5 = fmaf((C1).z, w1b, a5);             \
        a6 = fmaf((C1).w, w1a, a6); a7 = fmaf((C1).w, w1b, a7);             \
        a0 = fmaf(c2.x, w2a, a0); a1 = fmaf(c2.x, w2b, a1);                 \
        a2 = fmaf(c2.x, w2c, a2); a3 = fmaf(c2.x, w2d, a3);                 \
        a4 = fmaf(c2.y, w2a, a4); a5 = fmaf(c2.y, w2b, a5);                 \
        a6 = fmaf(c2.y, w2c, a6); a7 = fmaf(c2.y, w2d, a7);                 \
        a0 = fmaf(c3, w3[0], a0); a1 = fmaf(c3, w3[1], a1);                 \
        a2 = fmaf(c3, w3[2], a2); a3 = fmaf(c3, w3[3], a3);                 \
        a4 = fmaf(c3, w3[4], a4); a5 = fmaf(c3, w3[5], a5);                 \
        a6 = fmaf(c3, w3[6], a6); a7 = fmaf(c3, w3[7], a7);                 \
        _Pragma("unroll")                                                   \
        for (int e_ = 4; e_ <= 10; ++e_) {                                  \
            const int   i_ = e_ - 4;                                        \
            const float c_ = (i_ == 0) ? c4 : (i_ == 1) ? c5 :              \
                             (i_ == 2) ? c6 : (i_ == 3) ? c7 :              \
                             (i_ == 4) ? c8 : (i_ == 5) ? c9 : c10;         \
            const float4 k0 = *reinterpret_cast<const float4*>(&wl[kbA[i_]]);   \
            const float4 k1 = *reinterpret_cast<const float4*>(&wl[kbA[i_] + 4]);\
            a0 = fmaf(c_, k0.x, a0); a1 = fmaf(c_, k0.y, a1);               \
            a2 = fmaf(c_, k0.z, a2); a3 = fmaf(c_, k0.w, a3);               \
            a4 = fmaf(c_, k1.x, a4); a5 = fmaf(c_, k1.y, a5);               \
            a6 = fmaf(c_, k1.z, a6); a7 = fmaf(c_, k1.w, a7);               \
        }                                                                   \
        float4* o4 = reinterpret_cast<float4*>((OROW) + ((IT) << 11));      \
        o4[0] = make_float4(a0, a1, a2, a3);                                \
        o4[1] = make_float4(a4, a5, a6, a7);                                \
    } while (0)

#define TSC_COMPUTE(DLB, CA, CB, CC, CD, OROW) do {                         \
        TSC_ITER(DLB, 0, CA, OROW);                                         \
        TSC_ITER(DLB, 1, CB, OROW);                                         \
        TSC_ITER(DLB, 2, CC, OROW);                                         \
        TSC_ITER(DLB, 3, CD, OROW);                                         \
    } while (0)

    float4 A0, A1, A2, A3;      // e=1 regs, chunks 0 & 2
    float4 B0, B1, B2, B3;      // e=1 regs, chunks 1 & 3

    // Prologue: chunks 0 and 1 issued back-to-back (16 VMEM ops in flight).
    dma(dr0, 0, dL[0]);  TSC_LDE1(dr0, 0, A0, A1, A2, A3);
    dma(dr0, 1, dL[1]);  TSC_LDE1(dr0, 1, B0, B1, B2, B3);

    float* o0 = out + (size_t)b0 * TSC_OUT_LEN + j8;
    float* o1 = o0 + TSC_OUT_LEN;

    // chunk 0: (row b0, half 0)
    TSC_WAIT8();   // c0's 8 ops done; c1's 8 in flight
    TSC_BAR();
    TSC_COMPUTE(dL[0], A0, A1, A2, A3, o0);

    // chunk 1: (row b0, half 1)
    TSC_WAIT8();   // outstanding: [c1(8)][stores c0(8)] -> c1 done
    TSC_BAR();     // all waves done reading dL[0]
    dma(dr1, 0, dL[0]);  TSC_LDE1(dr1, 0, A0, A1, A2, A3);   // chunk 2
    TSC_COMPUTE(dL[1], B0, B1, B2, B3, o0 + 8192);

    // chunk 2: (row b0+1, half 0)
    TSC_WAIT8();   // outstanding: [c2(8)][stores c1(8)] -> c2 done
    TSC_BAR();     // all waves done reading dL[1]
    dma(dr1, 1, dL[1]);  TSC_LDE1(dr1, 1, B0, B1, B2, B3);   // chunk 3
    TSC_COMPUTE(dL[0], A0, A1, A2, A3, o1);

    // chunk 3: (row b0+1, half 1)
    TSC_WAIT8();   // outstanding: [c3(8)][stores c2(8)] -> c3 done
    TSC_BAR();
    TSC_COMPUTE(dL[1], B0, B1, B2, B3, o1 + 8192);

#undef TSC_COMPUTE
#undef TSC_ITER
#undef TSC_LDE1
}

extern "C" void kernel_launch(void* const* d_in, const int* in_sizes, int n_in,
                              void* d_out, int out_size, void* d_ws, size_t ws_size,
                              hipStream_t stream) {
    const float* data    = (const float*)d_in[0];
    const float* weights = (const float*)d_in[1];
    const float* bias    = (const float*)d_in[2];
    float* out = (float*)d_out;

    const int B = in_sizes[0] / TSC_ENC_LEN;   // 2048
    dim3 grid(B / 2);                          // 1024 persistent blocks, 4 chunks each
    dim3 block(256);
    tsc_transpose_kernel<<<grid, block, 0, stream>>>(data, weights, bias, out);
}